// Round 1
// baseline (233.095 us; speedup 1.0000x reference)
//
#include <hip/hip_runtime.h>
#include <math.h>

#define TN 8192
#define AN 128

// ---- workspace layout (doubles) ----
#define WS_COLSUM   0      // 128
#define WS_SUMSTD_B 128    // 64 banked accumulators
#define WS_CONC_B   192    // 64
#define WS_SUM10_B  256    // 64
#define WS_STD0     320
#define WS_STDL     321
#define WS_CNT20    322
#define WS_SUM10L5  323
#define WS_LAMBDA   324
#define WS_CSUM     325
#define WS_CTRACE   326
#define WS_CABS     327
#define WS_SEV      328
#define WS_COV      384            // 16384 doubles (gram accumulators)
#define WS_ZERO_N   (WS_COV + AN*AN)   // 16768 doubles to zero
// corr (float[16384]) lives right after the doubles

__global__ void k_zero(double* wsd) {
  int i = blockIdx.x * 256 + threadIdx.x;
  if (i < WS_ZERO_N) wsd[i] = 0.0;
}

// column sums (for means): 64 blocks x 128 threads, 128 rows each
__global__ void k_colsum(const float* __restrict__ x, double* __restrict__ wsd) {
  int c = threadIdx.x;
  int r0 = blockIdx.x * (TN / 64);
  double s = 0.0;
  for (int r = r0; r < r0 + TN / 64; ++r) s += (double)x[r * AN + c];
  atomicAdd(&wsd[WS_COLSUM + c], s);
}

// Gram matrix X^T X, fp32 accumulate per 512-row slice, fp64 atomic combine.
// grid (2, 8, 16), block 256: thread -> (i, j-quad), bz -> t-slice
__global__ void __launch_bounds__(256) k_gram(const float* __restrict__ x,
                                              double* __restrict__ wsd) {
  int tid = threadIdx.x;
  int iq = tid >> 4;
  int jq = tid & 15;
  int i = blockIdx.y * 16 + iq;
  int j4 = (blockIdx.x * 16 + jq) * 4;
  const float* p = x + (size_t)blockIdx.z * (TN / 16) * AN;
  float g0 = 0.f, g1 = 0.f, g2 = 0.f, g3 = 0.f;
#pragma unroll 4
  for (int t = 0; t < TN / 16; ++t, p += AN) {
    float xi = p[i];
    float4 xj = *(const float4*)(p + j4);
    g0 = fmaf(xi, xj.x, g0);
    g1 = fmaf(xi, xj.y, g1);
    g2 = fmaf(xi, xj.z, g2);
    g3 = fmaf(xi, xj.w, g3);
  }
  double* cov = wsd + WS_COV + i * AN + j4;
  atomicAdd(cov + 0, (double)g0);
  atomicAdd(cov + 1, (double)g1);
  atomicAdd(cov + 2, (double)g2);
  atomicAdd(cov + 3, (double)g3);
}

// normalize gram -> corr (float), and reduce sum / sum|.| / trace. Single block.
__global__ void __launch_bounds__(256) k_corrfin(double* __restrict__ wsd,
                                                 float* __restrict__ corr) {
  __shared__ double dsh[AN];
  __shared__ double msh[AN];
  __shared__ double r0[256], r1[256], r2[256];
  int p = threadIdx.x;
  if (p < AN) {
    double mu = wsd[WS_COLSUM + p] / (double)TN;
    msh[p] = mu;
    double cv = wsd[WS_COV + p * AN + p] - (double)TN * mu * mu;
    dsh[p] = sqrt(cv);
  }
  __syncthreads();
  double sa = 0.0, sb = 0.0, st = 0.0;
  for (int idx = p; idx < AN * AN; idx += 256) {
    int i = idx >> 7, j = idx & (AN - 1);
    double cv = wsd[WS_COV + idx] - (double)TN * msh[i] * msh[j];
    double c = cv / (dsh[i] * dsh[j]);
    corr[idx] = (float)c;
    sa += c;
    sb += fabs(c);
    if (i == j) st += c;
  }
  r0[p] = sa; r1[p] = sb; r2[p] = st;
  __syncthreads();
  for (int s = 128; s; s >>= 1) {
    if (p < s) { r0[p] += r0[p + s]; r1[p] += r1[p + s]; r2[p] += r2[p + s]; }
    __syncthreads();
  }
  if (p == 0) {
    wsd[WS_CSUM] = r0[0];
    wsd[WS_CABS] = r1[0];
    wsd[WS_CTRACE] = r2[0];
  }
}

// power iteration for lambda_max of corr. Single block, 256 threads
// (2 threads per row, half-row each, rows cached in registers).
__global__ void __launch_bounds__(256) k_power(const float* __restrict__ corr,
                                               double* __restrict__ wsd) {
  __shared__ float v[AN];
  __shared__ float part[256];
  __shared__ float un[AN];
  __shared__ float red[AN];
  int p = threadIdx.x;
  int i = p & (AN - 1);
  int h = p >> 7;
  float4 row[16];
  const float4* src = (const float4*)(corr + i * AN + h * 64);
#pragma unroll
  for (int k = 0; k < 16; ++k) row[k] = src[k];
  if (p < AN) v[p] = 1.0f;
  __syncthreads();
  float lam = 0.0f;
  for (int it = 0; it < 12; ++it) {
    const float4* vp = (const float4*)(v + h * 64);
    float acc = 0.f;
#pragma unroll
    for (int k = 0; k < 16; ++k) {
      float4 a = row[k], b = vp[k];
      acc += a.x * b.x + a.y * b.y + a.z * b.z + a.w * b.w;
    }
    part[p] = acc;
    __syncthreads();
    if (p < AN) {
      float u = part[p] + part[p + 128];
      un[p] = u;
      red[p] = u * u;
    }
    __syncthreads();
    for (int s = 64; s; s >>= 1) {
      if (p < s) red[p] += red[p + s];
      __syncthreads();
    }
    lam = sqrtf(red[0]);
    if (p < AN) v[p] = un[p] / lam;
    __syncthreads();
  }
  if (p == 0) wsd[WS_LAMBDA] = (double)lam;
}

// per-row: cross-sectional std (ddof=1) + exact sign-class counts.
// one wave per row; 2048 blocks x 256 threads
__global__ void __launch_bounds__(256) k_rowstats(const float* __restrict__ x,
                                                  double* __restrict__ wsd) {
  int lane = threadIdx.x & 63;
  int t = blockIdx.x * 4 + (threadIdx.x >> 6);
  const float* row = x + (size_t)t * AN;
  float x0 = row[lane], x1 = row[lane + 64];
  float s = x0 + x1;
#pragma unroll
  for (int o = 32; o; o >>= 1) s += __shfl_xor(s, o);
  float mean = s * (1.0f / AN);
  float d0 = x0 - mean, d1 = x1 - mean;
  float q = d0 * d0 + d1 * d1;
#pragma unroll
  for (int o = 32; o; o >>= 1) q += __shfl_xor(q, o);
  float sd = sqrtf(q / (float)(AN - 1));
  int pk = (int)(x0 < 0.f) + (int)(x1 < 0.f)
         + (((int)(x0 == 0.f) + (int)(x1 == 0.f)) << 10)
         + (((int)(x0 > 0.f) + (int)(x1 > 0.f)) << 20);
#pragma unroll
  for (int o = 32; o; o >>= 1) pk += __shfl_xor(pk, o);
  if (lane == 0) {
    int nn = pk & 1023, nz = (pk >> 10) & 1023, np = (pk >> 20) & 1023;
    int b = blockIdx.x & 63;
    atomicAdd(&wsd[WS_CONC_B + b],
              (double)nn * nn + (double)nz * nz + (double)np * np);
    atomicAdd(&wsd[WS_SUMSTD_B + b], (double)sd);
    if (t == 0) wsd[WS_STD0] = (double)sd;
    if (t == TN - 1) wsd[WS_STDL] = (double)sd;
  }
}

// rolling off-diagonal corr via C.sum() = sum_t (sum_i xc_ti/d_i)^2.
// one wave per window start; lane owns columns {lane, lane+64}
template <int W>
__global__ void __launch_bounds__(64) k_roll(const float* __restrict__ x,
                                             double* __restrict__ wsd) {
  int s = blockIdx.x;
  int lane = threadIdx.x;
  const float* base = x + (size_t)s * AN + lane;
  float x0[W], x1[W];
#pragma unroll
  for (int t = 0; t < W; ++t) {
    x0[t] = base[t * AN];
    x1[t] = base[t * AN + 64];
  }
  float s0 = 0.f, s1 = 0.f;
#pragma unroll
  for (int t = 0; t < W; ++t) { s0 += x0[t]; s1 += x1[t]; }
  float mu0 = s0 / W, mu1 = s1 / W;
  float v0 = 0.f, v1 = 0.f;
#pragma unroll
  for (int t = 0; t < W; ++t) {
    float a = x0[t] - mu0, b = x1[t] - mu1;
    v0 += a * a;
    v1 += b * b;
  }
  float a0 = 1.0f / sqrtf(v0), a1 = 1.0f / sqrtf(v1);
  float r = 0.f;
#pragma unroll
  for (int t = 0; t < W; ++t) {
    float pt = (x0[t] - mu0) * a0 + (x1[t] - mu1) * a1;
#pragma unroll
    for (int o = 32; o; o >>= 1) pt += __shfl_xor(pt, o);
    r += pt * pt;
  }
  if (lane == 0) {
    double off = ((double)r - (double)AN) / ((double)AN * (AN - 1));
    if (W == 20) {
      if (off > 0.7) atomicAdd(&wsd[WS_CNT20], 1.0);
    } else {
      atomicAdd(&wsd[WS_SUM10_B + (s & 63)], off);
      if (s >= TN - W - 5) atomicAdd(&wsd[WS_SUM10L5], off);
    }
  }
}

// tiny MLP (BatchNorm eval mode) -> softmax[2]
__global__ void __launch_bounds__(256) k_mlp(
    const float* __restrict__ x, const float* __restrict__ pos,
    const float* __restrict__ w1, const float* __restrict__ b1,
    const float* __restrict__ gamma, const float* __restrict__ beta,
    const float* __restrict__ w2, const float* __restrict__ b2,
    const float* __restrict__ w3, const float* __restrict__ b3,
    double* __restrict__ wsd) {
  __shared__ float f[2 * AN];
  __shared__ float h1[AN];
  __shared__ float h2[64];
  __shared__ float lg[3];
  int t = threadIdx.x;
  f[t] = (t < AN) ? x[(size_t)(TN - 1) * AN + t] : pos[t - AN];
  __syncthreads();
  if (t < AN) {
    float acc = b1[t];
    for (int k = 0; k < 2 * AN; ++k) acc = fmaf(f[k], w1[k * AN + t], acc);
    acc = fmaxf(acc, 0.0f);
    acc = gamma[t] * (acc / sqrtf(1.0f + 1e-5f)) + beta[t];
    h1[t] = acc;
  }
  __syncthreads();
  if (t < 64) {
    float acc = b2[t];
    for (int k = 0; k < AN; ++k) acc = fmaf(h1[k], w2[k * 64 + t], acc);
    h2[t] = fmaxf(acc, 0.0f);
  }
  __syncthreads();
  if (t < 3) {
    float acc = b3[t];
    for (int k = 0; k < 64; ++k) acc = fmaf(h2[k], w3[k * 3 + t], acc);
    lg[t] = acc;
  }
  __syncthreads();
  if (t == 0) {
    float m = fmaxf(lg[0], fmaxf(lg[1], lg[2]));
    float e0 = expf(lg[0] - m), e1 = expf(lg[1] - m), e2 = expf(lg[2] - m);
    wsd[WS_SEV] = (double)(e2 / (e0 + e1 + e2));
  }
}

// assemble the 8 outputs
__global__ void k_final(const double* __restrict__ wsd,
                        const float* __restrict__ pos,
                        float* __restrict__ out) {
  if (threadIdx.x != 0 || blockIdx.x != 0) return;
  double sumstd = 0.0, conc = 0.0, sum10 = 0.0;
  for (int k = 0; k < 64; ++k) {
    sumstd += wsd[WS_SUMSTD_B + k];
    conc += wsd[WS_CONC_B + k];
    sum10 += wsd[WS_SUM10_B + k];
  }
  // herding index
  double avg_disp = sumstd / (double)TN;
  double trend = -(wsd[WS_STDL] - wsd[WS_STD0]) / (double)(TN - 1);
  double hi = trend / (avg_disp + 1e-6) + 0.5;
  hi = fmin(1.0, fmax(0.0, hi));
  // synchronization
  double avg_corr = (wsd[WS_CSUM] - wsd[WS_CTRACE]) / ((double)AN * (AN - 1));
  double sync_ind = wsd[WS_LAMBDA] / (double)AN;
  double sync_risk = fmin(1.0, sync_ind * avg_corr);
  double pl = wsd[WS_CNT20] / (double)(TN - 20);
  // diversity
  double rd = 1.0 - wsd[WS_CABS] / ((double)AN * AN);
  double pasum = 0.0, pamax = 0.0;
  for (int k = 0; k < AN; ++k) {
    double pa = fabs((double)pos[k]);
    pasum += pa;
    if (pa > pamax) pamax = pa;
  }
  double pd = 1.0 - pamax / pasum;
  double dl = 1.0 - sqrt(rd * pd);
  // correlation surge
  double recent = wsd[WS_SUM10L5] / 5.0;
  double hist = (sum10 - wsd[WS_SUM10L5]) / (double)(TN - 10 - 5);
  double sraw = (recent - hist) / hist;
  sraw = fmin(1.0, fmax(0.0, sraw));
  double surge = (hist > 0.0) ? sraw : 0.0;
  // phase coupling
  double ac = (conc / (double)TN - (double)AN) / ((double)AN * (AN - 1));
  double pc = fmin(1.0, fmax(0.0, (ac - 0.5) * 2.0));
  double cr = (hi + sync_risk + dl) / 3.0;
  out[0] = (float)hi;
  out[1] = (float)wsd[WS_SEV];
  out[2] = (float)sync_risk;
  out[3] = (float)pl;
  out[4] = (float)dl;
  out[5] = (float)surge;
  out[6] = (float)pc;
  out[7] = (float)cr;
}

extern "C" void kernel_launch(void* const* d_in, const int* in_sizes, int n_in,
                              void* d_out, int out_size, void* d_ws, size_t ws_size,
                              hipStream_t stream) {
  const float* x     = (const float*)d_in[0];  // [8192,128]
  const float* pos   = (const float*)d_in[1];  // [128]
  const float* w1    = (const float*)d_in[2];  // [256,128]
  const float* b1    = (const float*)d_in[3];
  const float* gamma = (const float*)d_in[4];
  const float* beta  = (const float*)d_in[5];
  const float* w2    = (const float*)d_in[6];  // [128,64]
  const float* b2    = (const float*)d_in[7];
  const float* w3    = (const float*)d_in[8];  // [64,3]
  const float* b3    = (const float*)d_in[9];
  float* out = (float*)d_out;
  double* wsd = (double*)d_ws;
  float* corr = (float*)(wsd + WS_ZERO_N);  // 16384 floats

  k_zero<<<(WS_ZERO_N + 255) / 256, 256, 0, stream>>>(wsd);
  k_colsum<<<64, 128, 0, stream>>>(x, wsd);
  k_gram<<<dim3(2, 8, 16), 256, 0, stream>>>(x, wsd);
  k_corrfin<<<1, 256, 0, stream>>>(wsd, corr);
  k_power<<<1, 256, 0, stream>>>(corr, wsd);
  k_rowstats<<<TN / 4, 256, 0, stream>>>(x, wsd);
  k_roll<20><<<TN - 20, 64, 0, stream>>>(x, wsd);
  k_roll<10><<<TN - 10, 64, 0, stream>>>(x, wsd);
  k_mlp<<<1, 256, 0, stream>>>(x, pos, w1, b1, gamma, beta, w2, b2, w3, b3, wsd);
  k_final<<<1, 64, 0, stream>>>(wsd, pos, out);
}